// Round 1
// baseline (758.009 us; speedup 1.0000x reference)
//
#include <hip/hip_runtime.h>

#define NACT 200000
#define MPAD 200064          // ceil(NACT/128)*128
#define NBLK 1563            // MPAD/128
#define KOFF 27

typedef __bf16 bf16x8 __attribute__((ext_vector_type(8)));
typedef __bf16 bf16x4 __attribute__((ext_vector_type(4)));
typedef float f32x4 __attribute__((ext_vector_type(4)));

__device__ __forceinline__ void async_load16(const void* g, void* l) {
  __builtin_amdgcn_global_load_lds(
      (__attribute__((address_space(1))) void*)g,
      (__attribute__((address_space(3))) void*)l, 16, 0, 0);
}

// ---------------- rulebook inversion ----------------
__global__ void fill_g(int* __restrict__ G, float* __restrict__ st) {
  int i = blockIdx.x * 256 + threadIdx.x;
  if (i < KOFF * MPAD) G[i] = NACT;   // dummy row (zero features)
  if (i < 1024) st[i] = 0.f;          // zero stats/coeff scratch
}

__global__ void scatter_g(const int* __restrict__ ii, const int* __restrict__ oi,
                          int* __restrict__ G) {
  int i = blockIdx.x * 256 + threadIdx.x;
  if (i >= KOFF * NACT) return;
  int k = i / NACT;
  int o = oi[i];                  // pad entries: o == NACT, writes row NACT (benign)
  G[k * MPAD + o] = ii[i];
}

// ---------------- casts / transposes ----------------
__global__ void cast_feats(const float* __restrict__ F, __bf16* __restrict__ X) {
  int i = blockIdx.x * 256 + threadIdx.x;        // float4 groups, (NACT+1)*32
  if (i >= (NACT + 1) * 32) return;
  float4 v = (i < NACT * 32) ? ((const float4*)F)[i] : make_float4(0.f, 0.f, 0.f, 0.f);
  bf16x4 o = {(__bf16)v.x, (__bf16)v.y, (__bf16)v.z, (__bf16)v.w};
  *(bf16x4*)(X + (i << 2)) = o;
}

__global__ void prep_w(const float* __restrict__ W1, const float* __restrict__ W2,
                       __bf16* __restrict__ T1, __bf16* __restrict__ T2) {
  int i = blockIdx.x * 256 + threadIdx.x;        // WT[k][n][c] = W[k][c][n]
  if (i >= KOFF * 128 * 128) return;
  int k = i >> 14, rem = i & 16383, n = rem >> 7, c = rem & 127;
  int src = (k << 14) + (c << 7) + n;
  T1[i] = (__bf16)W1[src];
  T2[i] = (__bf16)W2[src];
}

// ---------------- gather-GEMM: Y[m,:] = sum_k X[G[k][m],:] @ W[k] ----------------
// 128x128 tile per block, 4 waves (2x2 of 64x64), BK=64, XOR-8 LDS swizzle.
__global__ __launch_bounds__(256, 2) void gemm_gather(
    const __bf16* __restrict__ X,   // [NACT+1][128], row NACT = 0
    const __bf16* __restrict__ WT,  // [27][128][128] : WT[k][n][c]
    const int* __restrict__ G,      // [27][MPAD]
    float* __restrict__ Y)          // [MPAD][128]
{
  __shared__ __bf16 Alds[128 * 64];
  __shared__ __bf16 Blds[128 * 64];
  const int t = threadIdx.x;
  const int lane = t & 63;
  const int w = t >> 6;
  const int wm = (w & 1) << 6;
  const int wn = (w >> 1) << 6;
  const int m_base = blockIdx.x << 7;
  const int r0 = t >> 3;   // staging row group 0..31
  const int scb = t & 7;   // lds 16B-chunk slot within row
  const int l15 = lane & 15;
  const int q4 = lane >> 4;

  f32x4 acc[4][4];
#pragma unroll
  for (int i = 0; i < 4; ++i)
#pragma unroll
    for (int j = 0; j < 4; ++j) acc[i][j] = (f32x4){0.f, 0.f, 0.f, 0.f};

  for (int kk = 0; kk < KOFF; ++kk) {
    int rowA[4];
#pragma unroll
    for (int j = 0; j < 4; ++j)
      rowA[j] = G[kk * MPAD + m_base + r0 + j * 32];
    const __bf16* wb = WT + (kk << 14);
#pragma unroll
    for (int s = 0; s < 2; ++s) {
      const int c0 = s << 6;
      __syncthreads();   // previous compute finished before LDS overwrite
#pragma unroll
      for (int j = 0; j < 4; ++j) {
        const int r = r0 + j * 32;
        const int gcb = scb ^ (r & 7);   // XOR-swizzle: lds slot scb <- global chunk gcb
        async_load16(wb + (r << 7) + c0 + (gcb << 3), &Blds[(((r << 3) + scb) << 3)]);
        async_load16(X + (rowA[j] << 7) + c0 + (gcb << 3), &Alds[(((r << 3) + scb) << 3)]);
      }
      __syncthreads();   // compiler emits vmcnt(0) drain for global_load_lds
#pragma unroll
      for (int ks = 0; ks < 2; ++ks) {
        bf16x8 af[4], bfr[4];
        const int cb0 = (ks << 2) + q4;
#pragma unroll
        for (int mi = 0; mi < 4; ++mi) {
          const int r = wm + mi * 16 + l15;
          af[mi] = *(const bf16x8*)&Alds[(((r << 3) + (cb0 ^ (r & 7))) << 3)];
        }
#pragma unroll
        for (int ni = 0; ni < 4; ++ni) {
          const int r = wn + ni * 16 + l15;
          bfr[ni] = *(const bf16x8*)&Blds[(((r << 3) + (cb0 ^ (r & 7))) << 3)];
        }
#pragma unroll
        for (int mi = 0; mi < 4; ++mi)
#pragma unroll
          for (int ni = 0; ni < 4; ++ni)
            acc[mi][ni] = __builtin_amdgcn_mfma_f32_16x16x32_bf16(
                af[mi], bfr[ni], acc[mi][ni], 0, 0, 0);
      }
    }
  }
  // epilogue: C/D layout col=lane&15, row=quad*4+reg
#pragma unroll
  for (int mi = 0; mi < 4; ++mi) {
#pragma unroll
    for (int ni = 0; ni < 4; ++ni) {
      const int col = wn + ni * 16 + l15;
#pragma unroll
      for (int rg = 0; rg < 4; ++rg) {
        const int row = m_base + wm + mi * 16 + (q4 << 2) + rg;
        Y[(row << 7) + col] = acc[mi][ni][rg];
      }
    }
  }
}

// ---------------- BN stats / coeffs / fused elementwise ----------------
__global__ void reduce_stats(const float* __restrict__ Y, float* __restrict__ st) {
  int c = threadIdx.x;  // 128
  float s = 0.f, s2 = 0.f;
  for (int r = blockIdx.x; r < NACT; r += gridDim.x) {
    float v = Y[(r << 7) + c];
    s += v; s2 += v * v;
  }
  atomicAdd(&st[c], s);
  atomicAdd(&st[128 + c], s2);
}

__global__ void bn_coeffs(const float* __restrict__ st, const float* __restrict__ gamma,
                          const float* __restrict__ beta, float* __restrict__ co) {
  int c = threadIdx.x;  // 128
  float m = st[c] * (1.f / NACT);
  float v = st[128 + c] * (1.f / NACT) - m * m;
  float sc = gamma[c] * rsqrtf(v + 1e-4f);
  co[c] = sc;
  co[128 + c] = beta[c] - m * sc;
}

__global__ void bn_relu_cast(const float* __restrict__ Y, const float* __restrict__ co,
                             __bf16* __restrict__ X2) {
  int i = blockIdx.x * 256 + threadIdx.x;
  if (i >= (NACT + 1) * 32) return;
  bf16x4 o;
  if (i < NACT * 32) {
    int cg = (i & 31) << 2;
    float4 v = ((const float4*)Y)[i];
    float a = fmaxf(fmaf(v.x, co[cg + 0], co[128 + cg + 0]), 0.f);
    float b = fmaxf(fmaf(v.y, co[cg + 1], co[128 + cg + 1]), 0.f);
    float d = fmaxf(fmaf(v.z, co[cg + 2], co[128 + cg + 2]), 0.f);
    float e = fmaxf(fmaf(v.w, co[cg + 3], co[128 + cg + 3]), 0.f);
    o = (bf16x4){(__bf16)a, (__bf16)b, (__bf16)d, (__bf16)e};
  } else {
    o = (bf16x4){(__bf16)0.f, (__bf16)0.f, (__bf16)0.f, (__bf16)0.f};
  }
  *(bf16x4*)(X2 + (i << 2)) = o;
}

__global__ void bn_add_relu(const float* __restrict__ Y, const float* __restrict__ co,
                            const float* __restrict__ F, float* __restrict__ O) {
  int i = blockIdx.x * 256 + threadIdx.x;
  if (i >= NACT * 32) return;
  int cg = (i & 31) << 2;
  float4 v = ((const float4*)Y)[i];
  float4 f = ((const float4*)F)[i];
  float4 o;
  o.x = fmaxf(fmaf(v.x, co[cg + 0], co[128 + cg + 0]) + f.x, 0.f);
  o.y = fmaxf(fmaf(v.y, co[cg + 1], co[128 + cg + 1]) + f.y, 0.f);
  o.z = fmaxf(fmaf(v.z, co[cg + 2], co[128 + cg + 2]) + f.z, 0.f);
  o.w = fmaxf(fmaf(v.w, co[cg + 3], co[128 + cg + 3]) + f.w, 0.f);
  ((float4*)O)[i] = o;
}

// ---------------- launcher ----------------
extern "C" void kernel_launch(void* const* d_in, const int* in_sizes, int n_in,
                              void* d_out, int out_size, void* d_ws, size_t ws_size,
                              hipStream_t stream) {
  const float* features = (const float*)d_in[0];
  const float* W1       = (const float*)d_in[1];
  const float* gamma1   = (const float*)d_in[2];
  const float* beta1    = (const float*)d_in[3];
  const float* W2       = (const float*)d_in[4];
  const float* gamma2   = (const float*)d_in[5];
  const float* beta2    = (const float*)d_in[6];
  const int* in_idx     = (const int*)d_in[7];
  const int* out_idx    = (const int*)d_in[8];

  char* ws = (char*)d_ws;
  size_t off = 0;
  int*    G  = (int*)(ws + off);    off += (size_t)KOFF * MPAD * 4;          // 21.6 MB
  __bf16* X1 = (__bf16*)(ws + off); off += (size_t)(NACT + 1) * 128 * 2;     // 51.2 MB
  __bf16* X2 = (__bf16*)(ws + off); off += (size_t)(NACT + 1) * 128 * 2;     // 51.2 MB
  __bf16* T1 = (__bf16*)(ws + off); off += (size_t)KOFF * 128 * 128 * 2;     // 0.88 MB
  __bf16* T2 = (__bf16*)(ws + off); off += (size_t)KOFF * 128 * 128 * 2;     // 0.88 MB
  float*  Y  = (float*)(ws + off);  off += (size_t)MPAD * 128 * 4;           // 102.4 MB
  float*  st = (float*)(ws + off);  off += 4096;
  // st: [0:256) stats1, [256:512) stats2, [512:768) coeffs1, [768:1024) coeffs2

  fill_g<<<(KOFF * MPAD + 255) / 256, 256, 0, stream>>>(G, st);
  scatter_g<<<(KOFF * NACT + 255) / 256, 256, 0, stream>>>(in_idx, out_idx, G);
  cast_feats<<<((NACT + 1) * 32 + 255) / 256, 256, 0, stream>>>(features, X1);
  prep_w<<<(KOFF * 128 * 128 + 255) / 256, 256, 0, stream>>>(W1, W2, T1, T2);

  gemm_gather<<<NBLK, 256, 0, stream>>>(X1, T1, G, Y);
  reduce_stats<<<1024, 128, 0, stream>>>(Y, st);
  bn_coeffs<<<1, 128, 0, stream>>>(st, gamma1, beta1, st + 512);
  bn_relu_cast<<<((NACT + 1) * 32 + 255) / 256, 256, 0, stream>>>(Y, st + 512, X2);

  gemm_gather<<<NBLK, 256, 0, stream>>>(X2, T2, G, Y);
  reduce_stats<<<1024, 128, 0, stream>>>(Y, st + 256);
  bn_coeffs<<<1, 128, 0, stream>>>(st + 256, gamma2, beta2, st + 768);
  bn_add_relu<<<(NACT * 32 + 255) / 256, 256, 0, stream>>>(Y, st + 768, features, (float*)d_out);
}

// Round 2
// 609.866 us; speedup vs baseline: 1.2429x; 1.2429x over previous
//
#include <hip/hip_runtime.h>

#define NACT 200000
#define MPAD 200064          // ceil(NACT/128)*128
#define NBLK 1563            // MPAD/128
#define KOFF 27

typedef __bf16 bf16x8 __attribute__((ext_vector_type(8)));
typedef __bf16 bf16x4 __attribute__((ext_vector_type(4)));
typedef float f32x4 __attribute__((ext_vector_type(4)));

__device__ __forceinline__ void async_load16(const void* g, void* l) {
  __builtin_amdgcn_global_load_lds(
      (__attribute__((address_space(1))) void*)g,
      (__attribute__((address_space(3))) void*)l, 16, 0, 0);
}

// ---------------- rulebook inversion ----------------
__global__ void fill_g(int* __restrict__ G) {
  int i = blockIdx.x * 256 + threadIdx.x;
  if (i < KOFF * MPAD) G[i] = NACT;   // dummy row (zero features)
}

__global__ void scatter_g(const int* __restrict__ ii, const int* __restrict__ oi,
                          int* __restrict__ G) {
  int i = blockIdx.x * 256 + threadIdx.x;
  if (i >= KOFF * NACT) return;
  int k = i / NACT;
  int o = oi[i];                  // pad entries: o == NACT -> row NACT (fixed below)
  G[k * MPAD + o] = ii[i];
}

// row NACT of G got polluted by pad entries; reset so Y row NACT is exactly 0
// (epilogue stats include padding rows and rely on them being zero).
__global__ void fix_g(int* __restrict__ G) {
  int k = threadIdx.x;
  if (k < KOFF) G[k * MPAD + NACT] = NACT;
}

// ---------------- casts / transposes ----------------
__global__ void cast_feats(const float* __restrict__ F, __bf16* __restrict__ X) {
  int i = blockIdx.x * 256 + threadIdx.x;        // float4 groups, (NACT+1)*32
  if (i >= (NACT + 1) * 32) return;
  float4 v = (i < NACT * 32) ? ((const float4*)F)[i] : make_float4(0.f, 0.f, 0.f, 0.f);
  bf16x4 o = {(__bf16)v.x, (__bf16)v.y, (__bf16)v.z, (__bf16)v.w};
  *(bf16x4*)(X + (i << 2)) = o;
}

__global__ void prep_w(const float* __restrict__ W1, const float* __restrict__ W2,
                       __bf16* __restrict__ T1, __bf16* __restrict__ T2) {
  int i = blockIdx.x * 256 + threadIdx.x;        // WT[k][n][c] = W[k][c][n]
  if (i >= KOFF * 128 * 128) return;
  int k = i >> 14, rem = i & 16383, n = rem >> 7, c = rem & 127;
  int src = (k << 14) + (c << 7) + n;
  T1[i] = (__bf16)W1[src];
  T2[i] = (__bf16)W2[src];
}

// ---------------- gather-GEMM: Y[m,:] = sum_k X[G[k][m],:] @ W[k] ----------------
// 128x128 tile per block, 4 waves (2x2 of 64x64), BK=64, XOR-8 LDS swizzle.
// Epilogue: bf16 Y stores + per-block column sum/sumsq partials (BN stats fused).
__global__ __launch_bounds__(256, 4) void gemm_gather(
    const __bf16* __restrict__ X,   // [NACT+1][128], row NACT = 0
    const __bf16* __restrict__ WT,  // [27][128][128] : WT[k][n][c]
    const int* __restrict__ G,      // [27][MPAD]
    __bf16* __restrict__ Y,         // [MPAD][128] bf16
    float* __restrict__ Pst)        // [256][NBLK]: (kind*128+col)*NBLK + block
{
  __shared__ __bf16 Alds[128 * 64];
  __shared__ __bf16 Blds[128 * 64];
  const int t = threadIdx.x;
  const int lane = t & 63;
  const int w = t >> 6;
  const int wm = (w & 1) << 6;
  const int wn = (w >> 1) << 6;
  const int m_base = blockIdx.x << 7;
  const int r0 = t >> 3;   // staging row group 0..31
  const int scb = t & 7;   // lds 16B-chunk slot within row
  const int l15 = lane & 15;
  const int q4 = lane >> 4;

  f32x4 acc[4][4];
#pragma unroll
  for (int i = 0; i < 4; ++i)
#pragma unroll
    for (int j = 0; j < 4; ++j) acc[i][j] = (f32x4){0.f, 0.f, 0.f, 0.f};

  for (int kk = 0; kk < KOFF; ++kk) {
    int rowA[4];
#pragma unroll
    for (int j = 0; j < 4; ++j)
      rowA[j] = G[kk * MPAD + m_base + r0 + j * 32];
    const __bf16* wb = WT + (kk << 14);
#pragma unroll
    for (int s = 0; s < 2; ++s) {
      const int c0 = s << 6;
      __syncthreads();   // previous compute finished before LDS overwrite
#pragma unroll
      for (int j = 0; j < 4; ++j) {
        const int r = r0 + j * 32;
        const int gcb = scb ^ (r & 7);   // XOR-swizzle: lds slot scb <- global chunk gcb
        async_load16(wb + (r << 7) + c0 + (gcb << 3), &Blds[(((r << 3) + scb) << 3)]);
        async_load16(X + (rowA[j] << 7) + c0 + (gcb << 3), &Alds[(((r << 3) + scb) << 3)]);
      }
      __syncthreads();   // compiler emits vmcnt(0) drain for global_load_lds
#pragma unroll
      for (int ks = 0; ks < 2; ++ks) {
        bf16x8 af[4], bfr[4];
        const int cb0 = (ks << 2) + q4;
#pragma unroll
        for (int mi = 0; mi < 4; ++mi) {
          const int r = wm + mi * 16 + l15;
          af[mi] = *(const bf16x8*)&Alds[(((r << 3) + (cb0 ^ (r & 7))) << 3)];
        }
#pragma unroll
        for (int ni = 0; ni < 4; ++ni) {
          const int r = wn + ni * 16 + l15;
          bfr[ni] = *(const bf16x8*)&Blds[(((r << 3) + (cb0 ^ (r & 7))) << 3)];
        }
#pragma unroll
        for (int mi = 0; mi < 4; ++mi)
#pragma unroll
          for (int ni = 0; ni < 4; ++ni)
            acc[mi][ni] = __builtin_amdgcn_mfma_f32_16x16x32_bf16(
                af[mi], bfr[ni], acc[mi][ni], 0, 0, 0);
      }
    }
  }

  // ---- epilogue 1: bf16 Y stores (C/D layout: col=lane&15, row=quad*4+reg) ----
#pragma unroll
  for (int mi = 0; mi < 4; ++mi) {
#pragma unroll
    for (int ni = 0; ni < 4; ++ni) {
      const int col = wn + ni * 16 + l15;
#pragma unroll
      for (int rg = 0; rg < 4; ++rg) {
        const int row = m_base + wm + mi * 16 + (q4 << 2) + rg;
        Y[(row << 7) + col] = (__bf16)acc[mi][ni][rg];
      }
    }
  }

  // ---- epilogue 2: BN stats partials (padding rows are zero -> harmless) ----
  float s[4], s2[4];
#pragma unroll
  for (int ni = 0; ni < 4; ++ni) {
    float a = 0.f, b = 0.f;
#pragma unroll
    for (int mi = 0; mi < 4; ++mi)
#pragma unroll
      for (int rg = 0; rg < 4; ++rg) {
        float v = acc[mi][ni][rg];
        a += v; b += v * v;
      }
    s[ni] = a; s2[ni] = b;
  }
#pragma unroll
  for (int ni = 0; ni < 4; ++ni) {
    s[ni]  += __shfl_xor(s[ni], 16);  s[ni]  += __shfl_xor(s[ni], 32);
    s2[ni] += __shfl_xor(s2[ni], 16); s2[ni] += __shfl_xor(s2[ni], 32);
  }
  float* sc = (float*)Alds;   // 512 floats scratch
  __syncthreads();
  if (q4 == 0) {
#pragma unroll
    for (int ni = 0; ni < 4; ++ni) {
      sc[(w << 6) + ni * 16 + l15]       = s[ni];
      sc[256 + (w << 6) + ni * 16 + l15] = s2[ni];
    }
  }
  __syncthreads();
  // t in [0,256): kind=t>>7, col=t&127; combine the two row-half waves
  {
    const int kind = t >> 7, col = t & 127;
    const int w1 = (col >> 6) << 1;
    const float v = sc[kind * 256 + (w1 << 6) + (col & 63)] +
                    sc[kind * 256 + ((w1 + 1) << 6) + (col & 63)];
    Pst[(size_t)t * NBLK + blockIdx.x] = v;
  }
}

// ---------------- stats tree-reduce + BN coeffs + fused elementwise ----------------
__global__ void stats_reduce(const float* __restrict__ P, float* __restrict__ st) {
  int b = blockIdx.x;              // 0..255 = kind*128+col
  const float* p = P + (size_t)b * NBLK;
  float s = 0.f;
  for (int i = threadIdx.x; i < NBLK; i += 256) s += p[i];
  for (int off = 32; off; off >>= 1) s += __shfl_down(s, off);
  __shared__ float ls[4];
  if ((threadIdx.x & 63) == 0) ls[threadIdx.x >> 6] = s;
  __syncthreads();
  if (threadIdx.x == 0) st[b] = ls[0] + ls[1] + ls[2] + ls[3];
}

__global__ void bn_coeffs(const float* __restrict__ st, const float* __restrict__ gamma,
                          const float* __restrict__ beta, float* __restrict__ co) {
  int c = threadIdx.x;  // 128
  float m = st[c] * (1.f / NACT);
  float v = st[128 + c] * (1.f / NACT) - m * m;
  float sc = gamma[c] * rsqrtf(v + 1e-4f);
  co[c] = sc;
  co[128 + c] = beta[c] - m * sc;
}

__global__ void bn_relu_cast(const __bf16* __restrict__ Y, const float* __restrict__ co,
                             __bf16* __restrict__ X2) {
  int i = blockIdx.x * 256 + threadIdx.x;   // 8-elem chunks, (NACT+1)*16
  if (i >= (NACT + 1) * 16) return;
  bf16x8 o;
  if (i < NACT * 16) {
    bf16x8 v = ((const bf16x8*)Y)[i];
    int cg = (i & 15) << 3;
#pragma unroll
    for (int e = 0; e < 8; ++e) {
      float x = fmaf((float)v[e], co[cg + e], co[128 + cg + e]);
      o[e] = (__bf16)fmaxf(x, 0.f);
    }
  } else {
#pragma unroll
    for (int e = 0; e < 8; ++e) o[e] = (__bf16)0.f;
  }
  ((bf16x8*)X2)[i] = o;
}

__global__ void bn_add_relu(const __bf16* __restrict__ Y, const float* __restrict__ co,
                            const float* __restrict__ F, float* __restrict__ O) {
  int i = blockIdx.x * 256 + threadIdx.x;   // 8-elem chunks, NACT*16
  if (i >= NACT * 16) return;
  bf16x8 v = ((const bf16x8*)Y)[i];
  float4 f0 = ((const float4*)F)[2 * i];
  float4 f1 = ((const float4*)F)[2 * i + 1];
  int cg = (i & 15) << 3;
  float4 o0, o1;
  o0.x = fmaxf(fmaf((float)v[0], co[cg + 0], co[128 + cg + 0]) + f0.x, 0.f);
  o0.y = fmaxf(fmaf((float)v[1], co[cg + 1], co[128 + cg + 1]) + f0.y, 0.f);
  o0.z = fmaxf(fmaf((float)v[2], co[cg + 2], co[128 + cg + 2]) + f0.z, 0.f);
  o0.w = fmaxf(fmaf((float)v[3], co[cg + 3], co[128 + cg + 3]) + f0.w, 0.f);
  o1.x = fmaxf(fmaf((float)v[4], co[cg + 4], co[128 + cg + 4]) + f1.x, 0.f);
  o1.y = fmaxf(fmaf((float)v[5], co[cg + 5], co[128 + cg + 5]) + f1.y, 0.f);
  o1.z = fmaxf(fmaf((float)v[6], co[cg + 6], co[128 + cg + 6]) + f1.z, 0.f);
  o1.w = fmaxf(fmaf((float)v[7], co[cg + 7], co[128 + cg + 7]) + f1.w, 0.f);
  ((float4*)O)[2 * i] = o0;
  ((float4*)O)[2 * i + 1] = o1;
}

// ---------------- launcher ----------------
extern "C" void kernel_launch(void* const* d_in, const int* in_sizes, int n_in,
                              void* d_out, int out_size, void* d_ws, size_t ws_size,
                              hipStream_t stream) {
  const float* features = (const float*)d_in[0];
  const float* W1       = (const float*)d_in[1];
  const float* gamma1   = (const float*)d_in[2];
  const float* beta1    = (const float*)d_in[3];
  const float* W2       = (const float*)d_in[4];
  const float* gamma2   = (const float*)d_in[5];
  const float* beta2    = (const float*)d_in[6];
  const int* in_idx     = (const int*)d_in[7];
  const int* out_idx    = (const int*)d_in[8];

  char* ws = (char*)d_ws;
  size_t off = 0;
  int*    G   = (int*)(ws + off);    off += (size_t)KOFF * MPAD * 4;          // 21.6 MB
  __bf16* X   = (__bf16*)(ws + off); off += (size_t)(NACT + 1) * 128 * 2;     // 51.2 MB (X1, reused as X2)
  __bf16* T1  = (__bf16*)(ws + off); off += (size_t)KOFF * 128 * 128 * 2;     // 0.88 MB
  __bf16* T2  = (__bf16*)(ws + off); off += (size_t)KOFF * 128 * 128 * 2;     // 0.88 MB
  __bf16* Y   = (__bf16*)(ws + off); off += (size_t)MPAD * 128 * 2;           // 51.2 MB (Y1, reused as Y2)
  float*  Pst = (float*)(ws + off);  off += (size_t)256 * NBLK * 4;           // 1.6 MB
  float*  st  = (float*)(ws + off);  off += 4096;
  // st: [0:256) stats, [512:768) coeffs1, [768:1024) coeffs2

  fill_g<<<(KOFF * MPAD + 255) / 256, 256, 0, stream>>>(G);
  scatter_g<<<(KOFF * NACT + 255) / 256, 256, 0, stream>>>(in_idx, out_idx, G);
  fix_g<<<1, 32, 0, stream>>>(G);
  cast_feats<<<((NACT + 1) * 32 + 255) / 256, 256, 0, stream>>>(features, X);
  prep_w<<<(KOFF * 128 * 128 + 255) / 256, 256, 0, stream>>>(W1, W2, T1, T2);

  gemm_gather<<<NBLK, 256, 0, stream>>>(X, T1, G, Y, Pst);
  stats_reduce<<<256, 256, 0, stream>>>(Pst, st);
  bn_coeffs<<<1, 128, 0, stream>>>(st, gamma1, beta1, st + 512);
  bn_relu_cast<<<((NACT + 1) * 16 + 255) / 256, 256, 0, stream>>>(Y, st + 512, X);

  gemm_gather<<<NBLK, 256, 0, stream>>>(X, T2, G, Y, Pst);
  stats_reduce<<<256, 256, 0, stream>>>(Pst, st);
  bn_coeffs<<<1, 128, 0, stream>>>(st, gamma2, beta2, st + 768);
  bn_add_relu<<<(NACT * 16 + 255) / 256, 256, 0, stream>>>(Y, st + 768, features, (float*)d_out);
}